// Round 7
// baseline (575.568 us; speedup 1.0000x reference)
//
#include <hip/hip_runtime.h>
#include <math.h>

constexpr int NN   = 100000;   // nodes
constexpr int DIM  = 128;
constexpr int NE   = 3200000;  // edges
constexpr int NCLS = 40;
constexpr float EPSF = 1e-7f;
constexpr int RNG   = 8;                        // col ranges == XCD count
constexpr int RSPAN = NN / RNG;                 // 12500

constexpr int FCH    = 2048;                    // edges per fill work-chunk
constexpr int NCHUNK = (NE + FCH - 1) / FCH;    // 1563

constexpr int SCHUNK = 1024;                    // elems per scan block
constexpr int SNB = (NN + SCHUNK - 1) / SCHUNK; // 98 scan blocks

constexpr int QS   = 4;                         // class quarters in h_kernel
constexpr int QCLS = NCLS / QS;                 // 10 classes per quarter

// ---------------- deg: in-degree over col (self-loop added later as +1) ----
__global__ void deg_kernel(const int4* __restrict__ col4, int* __restrict__ deg) {
    int i = blockIdx.x * blockDim.x + threadIdx.x;
    if (i < NE / 4) {
        int4 c = col4[i];
        atomicAdd(&deg[c.x], 1);
        atomicAdd(&deg[c.y], 1);
        atomicAdd(&deg[c.z], 1);
        atomicAdd(&deg[c.w], 1);
    }
}

// ---- scan phase 1: per-block local exclusive scan + block sums -------------
__global__ __launch_bounds__(256) void scan1_kernel(const int* __restrict__ deg,
                                                    int* __restrict__ offs,
                                                    int* __restrict__ partial) {
    __shared__ int ts[256];
    int t = threadIdx.x;
    int base = blockIdx.x * SCHUNK + t * 4;
    int v[4] = {0, 0, 0, 0};
    if (base + 3 < NN) {
        int4 d = *reinterpret_cast<const int4*>(deg + base);
        v[0] = d.x; v[1] = d.y; v[2] = d.z; v[3] = d.w;
    } else {
        for (int j = 0; j < 4; ++j) if (base + j < NN) v[j] = deg[base + j];
    }
    int s = v[0] + v[1] + v[2] + v[3];
    ts[t] = s;
    __syncthreads();
    for (int d = 1; d < 256; d <<= 1) {
        int o = (t >= d) ? ts[t - d] : 0;
        __syncthreads();
        ts[t] += o;
        __syncthreads();
    }
    int run = ts[t] - s;
    int w[4];
    w[0] = run;
    w[1] = run + v[0];
    w[2] = w[1] + v[1];
    w[3] = w[2] + v[2];
    if (base + 3 < NN) {
        *reinterpret_cast<int4*>(offs + base) = make_int4(w[0], w[1], w[2], w[3]);
    } else {
        for (int j = 0; j < 4; ++j) if (base + j < NN) offs[base + j] = w[j];
    }
    if (t == 255) partial[blockIdx.x] = ts[255];
}

// ---- scan phase 2: exclusive scan of the 98 block sums ---------------------
__global__ __launch_bounds__(128) void scan2_kernel(int* __restrict__ partial,
                                                    int* __restrict__ offs_last) {
    __shared__ int ps[128];
    int t = threadIdx.x;
    int v = (t < SNB) ? partial[t] : 0;
    ps[t] = v;
    __syncthreads();
    for (int d = 1; d < 128; d <<= 1) {
        int o = (t >= d) ? ps[t - d] : 0;
        __syncthreads();
        ps[t] += o;
        __syncthreads();
    }
    if (t < SNB) partial[t] = ps[t] - v;
    if (t == 127) *offs_last = ps[127];
}

// ---- scan phase 3: add block offsets; seed cursor ---------------------------
__global__ __launch_bounds__(256) void scan3_kernel(int* __restrict__ offs,
                                                    int* __restrict__ cursor,
                                                    const int* __restrict__ partial) {
    int i = blockIdx.x * blockDim.x + threadIdx.x;
    if (i >= NN) return;
    int o = offs[i] + partial[i >> 10];
    offs[i] = o;
    cursor[i] = o;
}

// ------ bucket fill, TRUE XCD-spatial partitioning ---------------------------
// Each block reads its hardware XCC_ID and handles only cols in that XCD's
// range, claiming edge chunks from a per-range work counter. All writes to
// ebuf window r therefore come from XCD r's L2 only -> single writeback/line.
__global__ __launch_bounds__(256) void fill_kernel(const int* __restrict__ row,
                                                   const int* __restrict__ col,
                                                   int* __restrict__ cursor,
                                                   int* __restrict__ ebuf,
                                                   int* __restrict__ work) {
    unsigned xcc;
    asm("s_getreg_b32 %0, hwreg(HW_REG_XCC_ID)" : "=s"(xcc));
    int range = (int)(xcc & (RNG - 1));
    int r0 = range * RSPAN;
    __shared__ int chunk_s;
    for (;;) {
        if (threadIdx.x == 0) chunk_s = atomicAdd(&work[range], 1);
        __syncthreads();
        int chunk = chunk_s;
        __syncthreads();
        if (chunk >= NCHUNK) break;
        int lo = chunk * FCH + threadIdx.x;
        int hi = min(chunk * FCH + FCH, NE);
#pragma unroll
        for (int e = lo; e < hi; e += 256) {
            int c = col[e];
            if ((unsigned)(c - r0) < (unsigned)RSPAN) {
                int pos = atomicAdd(&cursor[c], 1);
                ebuf[pos] = row[e];
            }
        }
    }
}

// ---------------- h = concat(xE, logH, logS) @ W ; g = h * dinv -------------
__global__ __launch_bounds__(256) void h_kernel(
    const float* __restrict__ xE, const float* __restrict__ xH,
    const float* __restrict__ xS, const float* __restrict__ W,
    const int* __restrict__ offs, float* __restrict__ g) {

    int lane = threadIdx.x & 63;
    int q = __builtin_amdgcn_readfirstlane(threadIdx.x >> 6);  // wave-uniform
    int n = blockIdx.x * 64 + lane;
    if (n >= NN) return;
    const float* Wq = W + q * QCLS;    // columns [q*10, q*10+10)

    float acc[QCLS];
#pragma unroll
    for (int c = 0; c < QCLS; ++c) acc[c] = 0.f;

    auto accum_row = [&](const float* __restrict__ xrow, int wbase,
                         float scale, bool zero_first) {
        const float4* x4 = reinterpret_cast<const float4*>(xrow);
        for (int k4 = 0; k4 < DIM / 4; ++k4) {
            float4 xv = x4[k4];
            float xs[4] = {xv.x, xv.y, xv.z, xv.w};
#pragma unroll
            for (int j = 0; j < 4; ++j) {
                int k = k4 * 4 + j;
                float xk = xs[j] * scale;
                if (zero_first && k4 == 0 && j == 0) xk = 0.f;
                const float* wr = &Wq[(wbase + k) * NCLS];
#pragma unroll
                for (int c = 0; c < QCLS; ++c)
                    acc[c] = fmaf(xk, wr[c], acc[c]);
            }
        }
    };

    accum_row(xE + (long)n * DIM, 0, 1.0f, false);
    {
        float x0 = xH[(long)n * DIM];
        float sH = acoshf(fmaxf(x0, 1.f)) * rsqrtf(fmaxf(x0 * x0 - 1.f, EPSF));
        accum_row(xH + (long)n * DIM, DIM, sH, true);
    }
    {
        float c0 = xS[(long)n * DIM];
        float cc = fminf(fmaxf(c0, -1.f), 1.f);
        float sS = acosf(cc) * rsqrtf(fmaxf(1.f - c0 * c0, EPSF));
        accum_row(xS + (long)n * DIM, 2 * DIM, sS, true);
    }

    float dinv = rsqrtf((float)(offs[n + 1] - offs[n] + 1));  // +1 self loop
    float* gn = g + (long)n * NCLS + q * QCLS;
#pragma unroll
    for (int c2 = 0; c2 < QCLS / 2; ++c2) {
        float2 o = make_float2(acc[c2 * 2] * dinv, acc[c2 * 2 + 1] * dinv);
        *reinterpret_cast<float2*>(gn + c2 * 2) = o;
    }
}

// ------ gather: float4 per thread (10 threads/node), 4x unrolled edge loop ---
__global__ __launch_bounds__(256) void gather_kernel(
    const int* __restrict__ offs, const int* __restrict__ ebuf,
    const float* __restrict__ g, float* __restrict__ out) {
    int t = blockIdx.x * blockDim.x + threadIdx.x;
    if (t >= NN * (NCLS / 4)) return;
    int n  = t / (NCLS / 4);
    int c4 = t - n * (NCLS / 4);

    int s = offs[n], e = offs[n + 1];
    float dinv = rsqrtf((float)(e - s + 1));
    const float4* g4 = reinterpret_cast<const float4*>(g);
    float4 a = g4[n * (NCLS / 4) + c4];      // self loop (dinv[n] folded in g)
    float ax = a.x, ay = a.y, az = a.z, aw = a.w;
    float bx = 0.f, by = 0.f, bz = 0.f, bw = 0.f;
    float cx = 0.f, cy = 0.f, cz = 0.f, cw = 0.f;
    float dx = 0.f, dy = 0.f, dz = 0.f, dw = 0.f;
    int j = s;
    for (; j + 3 < e; j += 4) {
        int r0 = ebuf[j], r1 = ebuf[j + 1], r2 = ebuf[j + 2], r3 = ebuf[j + 3];
        float4 v0 = g4[r0 * (NCLS / 4) + c4];
        float4 v1 = g4[r1 * (NCLS / 4) + c4];
        float4 v2 = g4[r2 * (NCLS / 4) + c4];
        float4 v3 = g4[r3 * (NCLS / 4) + c4];
        ax += v0.x; ay += v0.y; az += v0.z; aw += v0.w;
        bx += v1.x; by += v1.y; bz += v1.z; bw += v1.w;
        cx += v2.x; cy += v2.y; cz += v2.z; cw += v2.w;
        dx += v3.x; dy += v3.y; dz += v3.z; dw += v3.w;
    }
    for (; j < e; ++j) {
        float4 v = g4[ebuf[j] * (NCLS / 4) + c4];
        ax += v.x; ay += v.y; az += v.z; aw += v.w;
    }
    float4 o;
    o.x = (ax + bx + cx + dx) * dinv;
    o.y = (ay + by + cy + dy) * dinv;
    o.z = (az + bz + cz + dz) * dinv;
    o.w = (aw + bw + cw + dw) * dinv;
    reinterpret_cast<float4*>(out)[t] = o;
}

extern "C" void kernel_launch(void* const* d_in, const int* in_sizes, int n_in,
                              void* d_out, int out_size, void* d_ws, size_t ws_size,
                              hipStream_t stream) {
    const float* xE = (const float*)d_in[0];
    const float* xH = (const float*)d_in[1];
    const float* xS = (const float*)d_in[2];
    const float* W  = (const float*)d_in[3];
    const int*   ei = (const int*)d_in[4];
    const int* row = ei;            // edge_index[0]
    const int* col = ei + NE;       // edge_index[1]
    float* out = (float*)d_out;

    auto pad = [](size_t x) { return (x + 255) & ~(size_t)255; };
    char* p = (char*)d_ws;
    int* deg     = (int*)p;                p += pad((size_t)NN * 4);
    int* work    = (int*)p;                p += 256;   // RNG counters
    int* offs    = (int*)p;                p += pad((size_t)(NN + 1) * 4);
    int* cursor  = (int*)p;                p += pad((size_t)NN * 4);
    int* partial = (int*)p;                p += pad((size_t)SNB * 4);
    int* ebuf    = (int*)p;                p += pad((size_t)NE * 4);
    float* g     = (float*)p;              // NN*NCLS floats

    // zero deg + work in one memset (contiguous)
    hipMemsetAsync(deg, 0, pad((size_t)NN * 4) + 256, stream);

    deg_kernel<<<(NE / 4 + 255) / 256, 256, 0, stream>>>((const int4*)col, deg);
    scan1_kernel<<<SNB, 256, 0, stream>>>(deg, offs, partial);
    scan2_kernel<<<1, 128, 0, stream>>>(partial, offs + NN);
    scan3_kernel<<<(NN + 255) / 256, 256, 0, stream>>>(offs, cursor, partial);
    fill_kernel<<<2048, 256, 0, stream>>>(row, col, cursor, ebuf, work);
    h_kernel<<<(NN + 63) / 64, 256, 0, stream>>>(xE, xH, xS, W, offs, g);
    gather_kernel<<<(NN * (NCLS / 4) + 255) / 256, 256, 0, stream>>>(offs, ebuf, g, out);
}

// Round 8
// 250.693 us; speedup vs baseline: 2.2959x; 2.2959x over previous
//
#include <hip/hip_runtime.h>
#include <math.h>

constexpr int NN   = 100000;   // nodes
constexpr int DIM  = 128;
constexpr int NE   = 3200000;  // edges
constexpr int NCLS = 40;
constexpr float EPSF = 1e-7f;

constexpr int BSH  = 9;                      // 512 cols per coarse bucket
constexpr int BSZ  = 1 << BSH;
constexpr int NBKT = (NN + BSZ - 1) >> BSH;  // 196
constexpr int CAP  = 18432;                  // bucket capacity (mean 16327, +16 sigma)
constexpr int AEPB = 4096;                   // edges per binA block
constexpr int ABLK = (NE + AEPB - 1) / AEPB; // 782

constexpr int QS   = 4;                      // class quarters in h_kernel
constexpr int QCLS = NCLS / QS;              // 10

// ---- pass A: coarse-bucket partition with LDS shuffle, coalesced run writes
__global__ __launch_bounds__(256) void binA_kernel(const int* __restrict__ row,
                                                   const int* __restrict__ col,
                                                   int* __restrict__ gcur,
                                                   unsigned* __restrict__ pairs) {
    __shared__ int hist[256];          // per-bucket count, then running cursor
    __shared__ int lofx[256];          // block-local exclusive offsets
    __shared__ int gbase[256];         // global reserved base (count-relative)
    __shared__ unsigned sortedw[AEPB]; // edges grouped by bucket
    __shared__ int dstg[AEPB];         // global dst for each sorted slot

    int t = threadIdx.x;
    int e0 = blockIdx.x * AEPB;
    int cnt = min(AEPB, NE - e0);

    hist[t] = 0;
    __syncthreads();
    for (int k = t; k < cnt; k += 256) atomicAdd(&hist[col[e0 + k] >> BSH], 1);
    __syncthreads();

    int h = hist[t];
    if (t < NBKT && h > 0) gbase[t] = atomicAdd(&gcur[t], h);
    lofx[t] = h;
    __syncthreads();
    for (int d = 1; d < 256; d <<= 1) {
        int o = (t >= d) ? lofx[t - d] : 0;
        __syncthreads();
        lofx[t] += o;
        __syncthreads();
    }
    int excl = lofx[t] - h;   // exclusive block-local offset (own slot only)
    lofx[t] = excl;
    hist[t] = excl;           // becomes running cursor
    __syncthreads();

    for (int k = t; k < cnt; k += 256) {
        int c = col[e0 + k], r = row[e0 + k];
        int b = c >> BSH;
        int pos = atomicAdd(&hist[b], 1);
        sortedw[pos] = ((unsigned)(c & (BSZ - 1)) << 17) | (unsigned)r;
        dstg[pos] = b * CAP + gbase[b] + (pos - lofx[b]);
    }
    __syncthreads();
    for (int k = t; k < cnt; k += 256) pairs[dstg[k]] = sortedw[k];
}

// ---- bucket-base exclusive scan (196 values, one block) --------------------
__global__ __launch_bounds__(256) void bscan_kernel(const int* __restrict__ gcur,
                                                    int* __restrict__ bbase) {
    __shared__ int sc[256];
    int t = threadIdx.x;
    int v = (t < NBKT) ? gcur[t] : 0;
    sc[t] = v;
    __syncthreads();
    for (int d = 1; d < 256; d <<= 1) {
        int o = (t >= d) ? sc[t - d] : 0;
        __syncthreads();
        sc[t] += o;
        __syncthreads();
    }
    if (t < NBKT) bbase[t] = sc[t] - v;
}

// ---- pass B: per-bucket counting sort in LDS; writes offs + coalesced ebuf -
__global__ __launch_bounds__(1024) void binB_kernel(const int* __restrict__ gcur,
                                                    const int* __restrict__ bbase,
                                                    const unsigned* __restrict__ pairs,
                                                    int* __restrict__ ebuf,
                                                    int* __restrict__ offs) {
    __shared__ unsigned in[CAP];   // 72 KB
    __shared__ int srow[CAP];      // 72 KB
    __shared__ int hist[512];      // per-col count -> running cursor
    __shared__ int sc[1024];       // scan temp

    int t = threadIdx.x;
    int b = blockIdx.x;
    int cnt = gcur[b];
    int base = bbase[b];
    const unsigned* pb = pairs + (size_t)b * CAP;

    for (int i = t; i < cnt; i += 1024) in[i] = pb[i];
    if (t < 512) hist[t] = 0;
    __syncthreads();
    for (int i = t; i < cnt; i += 1024) atomicAdd(&hist[in[i] >> 17], 1);
    __syncthreads();

    int v = (t < 512) ? hist[t] : 0;
    sc[t] = v;
    __syncthreads();
    for (int d = 1; d < 1024; d <<= 1) {
        int o = (t >= d) ? sc[t - d] : 0;
        __syncthreads();
        sc[t] += o;
        __syncthreads();
    }
    int excl = sc[t] - v;
    if (t < 512) {
        int c = (b << BSH) + t;
        if (c <= NN) offs[c] = base + excl;   // covers offs[NN]=NE in bucket 195
        hist[t] = excl;                        // running cursor
    }
    __syncthreads();
    for (int i = t; i < cnt; i += 1024) {
        unsigned w = in[i];
        int pos = atomicAdd(&hist[w >> 17], 1);
        srow[pos] = (int)(w & 0x1FFFFu);
    }
    __syncthreads();
    for (int i = t; i < cnt; i += 1024) ebuf[base + i] = srow[i];
}

// ---------------- h = concat(xE, logH, logS) @ W ; g = h * dinv -------------
__global__ __launch_bounds__(256) void h_kernel(
    const float* __restrict__ xE, const float* __restrict__ xH,
    const float* __restrict__ xS, const float* __restrict__ W,
    const int* __restrict__ offs, float* __restrict__ g) {

    int lane = threadIdx.x & 63;
    int q = __builtin_amdgcn_readfirstlane(threadIdx.x >> 6);  // wave-uniform
    int n = blockIdx.x * 64 + lane;
    if (n >= NN) return;
    const float* Wq = W + q * QCLS;    // columns [q*10, q*10+10)

    float acc[QCLS];
#pragma unroll
    for (int c = 0; c < QCLS; ++c) acc[c] = 0.f;

    auto accum_row = [&](const float* __restrict__ xrow, int wbase,
                         float scale, bool zero_first) {
        const float4* x4 = reinterpret_cast<const float4*>(xrow);
        for (int k4 = 0; k4 < DIM / 4; ++k4) {
            float4 xv = x4[k4];
            float xs[4] = {xv.x, xv.y, xv.z, xv.w};
#pragma unroll
            for (int j = 0; j < 4; ++j) {
                int k = k4 * 4 + j;
                float xk = xs[j] * scale;
                if (zero_first && k4 == 0 && j == 0) xk = 0.f;
                const float* wr = &Wq[(wbase + k) * NCLS];
#pragma unroll
                for (int c = 0; c < QCLS; ++c)
                    acc[c] = fmaf(xk, wr[c], acc[c]);
            }
        }
    };

    accum_row(xE + (long)n * DIM, 0, 1.0f, false);
    {
        float x0 = xH[(long)n * DIM];
        float sH = acoshf(fmaxf(x0, 1.f)) * rsqrtf(fmaxf(x0 * x0 - 1.f, EPSF));
        accum_row(xH + (long)n * DIM, DIM, sH, true);
    }
    {
        float c0 = xS[(long)n * DIM];
        float cc = fminf(fmaxf(c0, -1.f), 1.f);
        float sS = acosf(cc) * rsqrtf(fmaxf(1.f - c0 * c0, EPSF));
        accum_row(xS + (long)n * DIM, 2 * DIM, sS, true);
    }

    float dinv = rsqrtf((float)(offs[n + 1] - offs[n] + 1));  // +1 self loop
    float* gn = g + (long)n * NCLS + q * QCLS;
#pragma unroll
    for (int c2 = 0; c2 < QCLS / 2; ++c2) {
        float2 o = make_float2(acc[c2 * 2] * dinv, acc[c2 * 2 + 1] * dinv);
        *reinterpret_cast<float2*>(gn + c2 * 2) = o;
    }
}

// ------ gather: float4 per thread (10 threads/node), 4x unrolled edge loop ---
__global__ __launch_bounds__(256) void gather_kernel(
    const int* __restrict__ offs, const int* __restrict__ ebuf,
    const float* __restrict__ g, float* __restrict__ out) {
    int t = blockIdx.x * blockDim.x + threadIdx.x;
    if (t >= NN * (NCLS / 4)) return;
    int n  = t / (NCLS / 4);
    int c4 = t - n * (NCLS / 4);

    int s = offs[n], e = offs[n + 1];
    float dinv = rsqrtf((float)(e - s + 1));
    const float4* g4 = reinterpret_cast<const float4*>(g);
    float4 a = g4[n * (NCLS / 4) + c4];      // self loop (dinv[n] folded in g)
    float ax = a.x, ay = a.y, az = a.z, aw = a.w;
    float bx = 0.f, by = 0.f, bz = 0.f, bw = 0.f;
    float cx = 0.f, cy = 0.f, cz = 0.f, cw = 0.f;
    float dx = 0.f, dy = 0.f, dz = 0.f, dw = 0.f;
    int j = s;
    for (; j + 3 < e; j += 4) {
        int r0 = ebuf[j], r1 = ebuf[j + 1], r2 = ebuf[j + 2], r3 = ebuf[j + 3];
        float4 v0 = g4[r0 * (NCLS / 4) + c4];
        float4 v1 = g4[r1 * (NCLS / 4) + c4];
        float4 v2 = g4[r2 * (NCLS / 4) + c4];
        float4 v3 = g4[r3 * (NCLS / 4) + c4];
        ax += v0.x; ay += v0.y; az += v0.z; aw += v0.w;
        bx += v1.x; by += v1.y; bz += v1.z; bw += v1.w;
        cx += v2.x; cy += v2.y; cz += v2.z; cw += v2.w;
        dx += v3.x; dy += v3.y; dz += v3.z; dw += v3.w;
    }
    for (; j < e; ++j) {
        float4 v = g4[ebuf[j] * (NCLS / 4) + c4];
        ax += v.x; ay += v.y; az += v.z; aw += v.w;
    }
    float4 o;
    o.x = (ax + bx + cx + dx) * dinv;
    o.y = (ay + by + cy + dy) * dinv;
    o.z = (az + bz + cz + dz) * dinv;
    o.w = (aw + bw + cw + dw) * dinv;
    reinterpret_cast<float4*>(out)[t] = o;
}

extern "C" void kernel_launch(void* const* d_in, const int* in_sizes, int n_in,
                              void* d_out, int out_size, void* d_ws, size_t ws_size,
                              hipStream_t stream) {
    const float* xE = (const float*)d_in[0];
    const float* xH = (const float*)d_in[1];
    const float* xS = (const float*)d_in[2];
    const float* W  = (const float*)d_in[3];
    const int*   ei = (const int*)d_in[4];
    const int* row = ei;            // edge_index[0]
    const int* col = ei + NE;       // edge_index[1]
    float* out = (float*)d_out;

    auto pad = [](size_t x) { return (x + 255) & ~(size_t)255; };
    char* p = (char*)d_ws;
    int* gcur  = (int*)p;               p += pad((size_t)NBKT * 4);
    int* bbase = (int*)p;               p += pad((size_t)NBKT * 4);
    int* offs  = (int*)p;               p += pad((size_t)(NN + 1) * 4);
    int* ebuf  = (int*)p;               p += pad((size_t)NE * 4);
    float* g   = (float*)p;             // NN*NCLS floats (16 MB)
    unsigned* pairs = (unsigned*)g;     // aliases g: pairs dead before h writes g

    hipMemsetAsync(gcur, 0, (size_t)NBKT * 4, stream);

    binA_kernel<<<ABLK, 256, 0, stream>>>(row, col, gcur, pairs);
    bscan_kernel<<<1, 256, 0, stream>>>(gcur, bbase);
    binB_kernel<<<NBKT, 1024, 0, stream>>>(gcur, bbase, pairs, ebuf, offs);
    h_kernel<<<(NN + 63) / 64, 256, 0, stream>>>(xE, xH, xS, W, offs, g);
    gather_kernel<<<(NN * (NCLS / 4) + 255) / 256, 256, 0, stream>>>(offs, ebuf, g, out);
}